// Round 6
// baseline (580.386 us; speedup 1.0000x reference)
//
#include <hip/hip_runtime.h>
#include <math.h>

// Problem constants
constexpr int E = 8, H = 1024, DFF = 2048, T = 4096;
constexpr int TR = 8192;          // total routed rows = T * topk
constexpr int MAXJ = 72;          // max (expert, m-tile) jobs: 8192/128 + E

typedef __bf16 bf16x8 __attribute__((ext_vector_type(8)));
typedef __bf16 bf16x4 __attribute__((ext_vector_type(4)));
typedef float f32x4 __attribute__((ext_vector_type(4)));

__device__ __forceinline__ void gload16(const void* g, void* l) {
    __builtin_amdgcn_global_load_lds(
        (const __attribute__((address_space(1))) unsigned int*)g,
        (__attribute__((address_space(3))) unsigned int*)l, 16, 0, 0);
}

// ---------------- k1: affinity + top-2 (atomic-free) + x->bf16 ----------------
__global__ __launch_bounds__(256) void k1_affinity(
    const float* __restrict__ x, const float* __restrict__ cent,
    const float* __restrict__ bias,
    int* __restrict__ se, float* __restrict__ sw, __bf16* __restrict__ xb) {
    __shared__ float cs[E * H];
    int tid = threadIdx.x;
    for (int i = tid; i < E * H / 4; i += 256)
        ((float4*)cs)[i] = ((const float4*)cent)[i];
    __syncthreads();

    int wave = tid >> 6, lane = tid & 63;
    int t = blockIdx.x * 4 + wave;
    const float4* xr = (const float4*)(x + (size_t)t * H);
    bf16x4* xw = (bf16x4*)(xb + (size_t)t * H);
    float acc[E] = {};
    #pragma unroll
    for (int it = 0; it < 4; it++) {
        float4 xv = xr[lane + it * 64];
        bf16x4 o = {(__bf16)xv.x, (__bf16)xv.y, (__bf16)xv.z, (__bf16)xv.w};
        xw[lane + it * 64] = o;
        #pragma unroll
        for (int e = 0; e < E; e++) {
            float4 cv = ((const float4*)(cs + e * H))[lane + it * 64];
            acc[e] = fmaf(xv.x, cv.x, acc[e]);
            acc[e] = fmaf(xv.y, cv.y, acc[e]);
            acc[e] = fmaf(xv.z, cv.z, acc[e]);
            acc[e] = fmaf(xv.w, cv.w, acc[e]);
        }
    }
    #pragma unroll
    for (int off = 32; off; off >>= 1)
        #pragma unroll
        for (int e = 0; e < E; e++) acc[e] += __shfl_down(acc[e], off);

    if (lane == 0) {
        float s[E];
        #pragma unroll
        for (int e = 0; e < E; e++)
            s[e] = 1.0f / (1.0f + expf(-acc[e])) + bias[e];
        int i0 = 0;
        for (int e = 1; e < E; e++) if (s[e] > s[i0]) i0 = e;
        int i1 = -1;
        for (int e = 0; e < E; e++) {
            if (e == i0) continue;
            if (i1 < 0 || s[e] > s[i1]) i1 = e;
        }
        float m = fmaxf(s[i0], s[i1]);
        float w0 = expf(s[i0] - m), w1 = expf(s[i1] - m);
        float inv = 1.0f / (w0 + w1);
        se[2 * t] = i0;     sw[2 * t] = w0 * inv;
        se[2 * t + 1] = i1; sw[2 * t + 1] = w1 * inv;
    }
}

// ---------------- k1b: per-expert partition via block scan ----------------
__global__ __launch_bounds__(256) void k1b_partition(
    const int* __restrict__ se, const float* __restrict__ sw,
    int* __restrict__ token_list, float* __restrict__ roww,
    int* __restrict__ cnt) {
    int e = blockIdx.x;
    int tid = threadIdx.x;
    int wave = tid >> 6, lane = tid & 63;
    __shared__ int wsum[4];
    int running = 0;
    for (int c0 = 0; c0 < 2 * T; c0 += 256) {
        int i = c0 + tid;
        bool pred = (se[i] == e);
        unsigned long long mask = __ballot(pred);
        int pos_in_wave = __popcll(mask & ((1ull << lane) - 1ull));
        if (lane == 0) wsum[wave] = __popcll(mask);
        __syncthreads();
        int wbase = 0;
        for (int w2 = 0; w2 < wave; w2++) wbase += wsum[w2];
        int total = wsum[0] + wsum[1] + wsum[2] + wsum[3];
        if (pred) {
            int p = running + wbase + pos_in_wave;
            token_list[e * T + p] = i >> 1;
            roww[e * T + p] = sw[i];
        }
        running += total;
        __syncthreads();
    }
    if (tid == 0) cnt[e] = running;
}

// ---------------- k1.5: offsets + counts output + job table ----------------
__global__ void k15_offsets(const int* __restrict__ cnt, int* __restrict__ off,
                            float* __restrict__ out_counts,
                            int* __restrict__ jobs, int* __restrict__ njobs) {
    if (threadIdx.x == 0) {
        int acc = 0, nj = 0;
        for (int e = 0; e < E; e++) {
            off[e] = acc; acc += cnt[e];
            int mts = (cnt[e] + 127) >> 7;
            for (int mt = 0; mt < mts; mt++) jobs[nj++] = e * 64 + mt;
        }
        njobs[0] = nj;
    }
    if (threadIdx.x < E) out_counts[threadIdx.x] = (float)cnt[threadIdx.x];
}

// ---------------- conv: fp32 -> bf16 (single tensor) ----------------
__global__ __launch_bounds__(256) void k_conv(const float* __restrict__ in,
                                              __bf16* __restrict__ out, int n4) {
    int i = blockIdx.x * 256 + threadIdx.x;
    if (i < n4) {
        float4 v = ((const float4*)in)[i];
        bf16x4 o = {(__bf16)v.x, (__bf16)v.y, (__bf16)v.z, (__bf16)v.w};
        ((bf16x4*)out)[i] = o;
    }
}

// ---------------- conv2: gw, uw in one launch ----------------
__global__ __launch_bounds__(256) void k_conv2(
    const float* __restrict__ gw, __bf16* __restrict__ gwb,
    const float* __restrict__ uw, __bf16* __restrict__ uwb, int w4) {
    int i = blockIdx.x * 256 + threadIdx.x;
    const float* in; __bf16* out; int idx;
    if (i < w4) { in = gw; out = gwb; idx = i; }
    else { idx = i - w4; if (idx >= w4) return; in = uw; out = uwb; }
    float4 v = ((const float4*)in)[idx];
    bf16x4 o = {(__bf16)v.x, (__bf16)v.y, (__bf16)v.z, (__bf16)v.w};
    ((bf16x4*)out)[idx] = o;
}

// ---------------- k2: grouped GEMM gate+up (MFMA), BK=64, tile 128x128 dual ----------------
// 4 waves 2x2; 3 blocks/CU (LDS 48KB*3=144K <= 160K, VGPR <= 170).
__global__ __launch_bounds__(256, 3) void k2_gateup(
    const __bf16* __restrict__ xb, const __bf16* __restrict__ gwb,
    const __bf16* __restrict__ uwb, const int* __restrict__ cnt,
    const int* __restrict__ off, const int* __restrict__ token_list,
    const int* __restrict__ jobs, const int* __restrict__ njobs,
    __bf16* __restrict__ h) {
    int jt = blockIdx.x >> 4, nt = blockIdx.x & 15;   // nt: 0..15 (DFF/128)
    if (jt >= njobs[0]) return;
    int job = jobs[jt];
    int e = job >> 6, mt = job & 63;
    int Me = cnt[e], offe = off[e];

    __shared__ __bf16 As[128 * 64];   // 16 KB
    __shared__ __bf16 Bg[128 * 64];   // 16 KB
    __shared__ __bf16 Bu[128 * 64];   // 16 KB

    int tid = threadIdx.x;
    int lane = tid & 63, w = tid >> 6;
    int wm = w >> 1, wn = w & 1;

    // staging sources: LDS slot (row, l&7) receives global k-chunk (l&7)^(row&7)
    const __bf16* asrc[4];
    const __bf16 *bsg[4], *bsu[4];
    #pragma unroll
    for (int rr = 0; rr < 4; rr++) {
        int l = rr * 256 + tid;
        int row = l >> 3, sl = l & 7;
        int gr = mt * 128 + row; if (gr >= Me) gr = Me - 1;
        int tok = token_list[e * T + gr];
        asrc[rr] = xb + (size_t)tok * H + ((sl ^ (row & 7)) * 8);
        size_t base = ((size_t)e * DFF + nt * 128 + row) * H + ((sl ^ (row & 7)) * 8);
        bsg[rr] = gwb + base;
        bsu[rr] = uwb + base;
    }

    f32x4 accg[4][4] = {};
    f32x4 accu[4][4] = {};
    int kq = lane >> 4, m15 = lane & 15;

    for (int k0 = 0; k0 < H; k0 += 64) {
        #pragma unroll
        for (int rr = 0; rr < 4; rr++) {
            gload16(asrc[rr] + k0, &As[(rr * 256 + tid) * 8]);
            gload16(bsg[rr] + k0, &Bg[(rr * 256 + tid) * 8]);
            gload16(bsu[rr] + k0, &Bu[(rr * 256 + tid) * 8]);
        }
        __syncthreads();

        #pragma unroll
        for (int kc = 0; kc < 2; kc++) {
            bf16x8 af[4], gf[4], uf[4];
            #pragma unroll
            for (int i = 0; i < 4; i++) {
                int row = wm * 64 + i * 16 + m15;
                int sl = (kc * 4 + kq) ^ (row & 7);
                af[i] = *(const bf16x8*)&As[row * 64 + sl * 8];
            }
            #pragma unroll
            for (int j = 0; j < 4; j++) {
                int row = wn * 64 + j * 16 + m15;
                int sl = (kc * 4 + kq) ^ (row & 7);
                gf[j] = *(const bf16x8*)&Bg[row * 64 + sl * 8];
                uf[j] = *(const bf16x8*)&Bu[row * 64 + sl * 8];
            }
            #pragma unroll
            for (int i = 0; i < 4; i++)
                #pragma unroll
                for (int j = 0; j < 4; j++) {
                    accg[i][j] = __builtin_amdgcn_mfma_f32_16x16x32_bf16(af[i], gf[j], accg[i][j], 0, 0, 0);
                    accu[i][j] = __builtin_amdgcn_mfma_f32_16x16x32_bf16(af[i], uf[j], accu[i][j], 0, 0, 0);
                }
        }
        __syncthreads();
    }

    // epilogue: h = silu(g) * u
    #pragma unroll
    for (int i = 0; i < 4; i++)
        #pragma unroll
        for (int j = 0; j < 4; j++) {
            int nloc = wn * 64 + j * 16 + m15;
            size_t c = (size_t)nt * 128 + nloc;
            #pragma unroll
            for (int p = 0; p < 4; p++) {
                int mloc = wm * 64 + i * 16 + kq * 4 + p;
                int mrow = mt * 128 + mloc;
                if (mrow < Me) {
                    float g = accg[i][j][p], u = accu[i][j][p];
                    float sig = 1.0f / (1.0f + __expf(-g));
                    h[(size_t)(offe + mrow) * DFF + c] = (__bf16)(g * sig * u);
                }
            }
        }
}

// ---------------- k3: grouped GEMM down (MFMA), BK=64, tile 128x256 ----------------
// 512 threads, 8 waves (2m x 4n); weighted atomic scatter epilogue into out.
__global__ __launch_bounds__(512, 4) void k3_down(
    const __bf16* __restrict__ h, const __bf16* __restrict__ dwb,
    const int* __restrict__ cnt, const int* __restrict__ off,
    const int* __restrict__ token_list, const float* __restrict__ roww,
    const int* __restrict__ jobs, const int* __restrict__ njobs,
    float* __restrict__ out) {
    int jt = blockIdx.x >> 2, nt = blockIdx.x & 3;    // nt: 0..3 (H/256)
    if (jt >= njobs[0]) return;
    int job = jobs[jt];
    int e = job >> 6, mt = job & 63;
    int Me = cnt[e], offe = off[e];

    __shared__ __bf16 As[128 * 64];   // 16 KB
    __shared__ __bf16 Bs[256 * 64];   // 32 KB

    int tid = threadIdx.x;
    int lane = tid & 63, w = tid >> 6;
    int wm = w >> 2, wn = w & 3;

    const __bf16* asrc[2];
    #pragma unroll
    for (int rr = 0; rr < 2; rr++) {
        int l = rr * 512 + tid;
        int row = l >> 3, sl = l & 7;
        int koff = (sl ^ (row & 7)) * 8;
        int gr = mt * 128 + row; if (gr >= Me) gr = Me - 1;
        asrc[rr] = h + (size_t)(offe + gr) * DFF + koff;
    }
    const __bf16* bsrc[4];
    #pragma unroll
    for (int rr = 0; rr < 4; rr++) {
        int l = rr * 512 + tid;
        int row = l >> 3, sl = l & 7;
        int koff = (sl ^ (row & 7)) * 8;
        bsrc[rr] = dwb + ((size_t)e * H + nt * 256 + row) * DFF + koff;
    }

    f32x4 acc[4][4] = {};
    int kq = lane >> 4, m15 = lane & 15;

    for (int k0 = 0; k0 < DFF; k0 += 64) {
        #pragma unroll
        for (int rr = 0; rr < 2; rr++)
            gload16(asrc[rr] + k0, &As[(rr * 512 + tid) * 8]);
        #pragma unroll
        for (int rr = 0; rr < 4; rr++)
            gload16(bsrc[rr] + k0, &Bs[(rr * 512 + tid) * 8]);
        __syncthreads();

        #pragma unroll
        for (int kc = 0; kc < 2; kc++) {
            bf16x8 af[4], bf[4];
            #pragma unroll
            for (int i = 0; i < 4; i++) {
                int row = wm * 64 + i * 16 + m15;
                int sl = (kc * 4 + kq) ^ (row & 7);
                af[i] = *(const bf16x8*)&As[row * 64 + sl * 8];
            }
            #pragma unroll
            for (int j = 0; j < 4; j++) {
                int row = wn * 64 + j * 16 + m15;
                int sl = (kc * 4 + kq) ^ (row & 7);
                bf[j] = *(const bf16x8*)&Bs[row * 64 + sl * 8];
            }
            #pragma unroll
            for (int i = 0; i < 4; i++)
                #pragma unroll
                for (int j = 0; j < 4; j++)
                    acc[i][j] = __builtin_amdgcn_mfma_f32_16x16x32_bf16(af[i], bf[j], acc[i][j], 0, 0, 0);
        }
        __syncthreads();
    }

    // epilogue: out[tok, n] += w * acc   (each out element hit exactly topk=2 times)
    #pragma unroll
    for (int i = 0; i < 4; i++) {
        int mbase = mt * 128 + wm * 64 + i * 16 + kq * 4;
        #pragma unroll
        for (int p = 0; p < 4; p++) {
            int mrow = mbase + p;
            if (mrow >= Me) continue;
            int tok = token_list[e * T + mrow];
            float wgt = roww[e * T + mrow];
            float* orow = out + (size_t)tok * H;
            #pragma unroll
            for (int j = 0; j < 4; j++) {
                int nglob = nt * 256 + wn * 64 + j * 16 + m15;
                atomicAdd(&orow[nglob], wgt * acc[i][j][p]);
            }
        }
    }
}

// ---------------- launch ----------------
extern "C" void kernel_launch(void* const* d_in, const int* in_sizes, int n_in,
                              void* d_out, int out_size, void* d_ws, size_t ws_size,
                              hipStream_t stream) {
    const float* x    = (const float*)d_in[0];
    const float* cent = (const float*)d_in[1];
    const float* gw   = (const float*)d_in[2];
    const float* uw   = (const float*)d_in[3];
    const float* dw   = (const float*)d_in[4];
    const float* bias = (const float*)d_in[5];
    float* out = (float*)d_out;

    // workspace layout (bytes)
    char* ws = (char*)d_ws;
    int*   cnt        = (int*)(ws + 0);
    int*   off        = (int*)(ws + 64);
    int*   se         = (int*)(ws + 128);              // 32 KB
    float* sw         = (float*)(ws + 32896);          // 32 KB
    int*   token_list = (int*)(ws + 65664);            // 128 KB
    float* roww       = (float*)(ws + 196736);         // 128 KB
    int*   jobs       = (int*)(ws + 327808);           // 80 ints
    int*   njobs      = (int*)(ws + 328128);           // 1 int
    const size_t MB = 1u << 20;
    __bf16* gwb = (__bf16*)(ws + 1 * MB);              // 32 MB
    __bf16* uwb = (__bf16*)(ws + 1 * MB + 33554432);   // 32 MB
    __bf16* dwb = uwb;                                 // alias: uwb dead after k2
    __bf16* xb  = (__bf16*)(ws + 1 * MB + 67108864);   // 8 MB
    __bf16* h   = (__bf16*)(ws + 1 * MB + 75497472);   // 32 MB

    const int W4 = E * DFF * H / 4;

    hipMemsetAsync(out, 0, (size_t)T * H * sizeof(float), stream);
    k_conv2<<<(2 * W4 + 255) / 256, 256, 0, stream>>>(gw, gwb, uw, uwb, W4);
    k1_affinity<<<T / 4, 256, 0, stream>>>(x, cent, bias, se, sw, xb);
    k1b_partition<<<E, 256, 0, stream>>>(se, sw, token_list, roww, cnt);
    k15_offsets<<<1, 64, 0, stream>>>(cnt, off, out + (size_t)T * H, jobs, njobs);
    k2_gateup<<<MAXJ * 16, 256, 0, stream>>>(xb, gwb, uwb, cnt, off, token_list, jobs, njobs, h);
    k_conv<<<(W4 + 255) / 256, 256, 0, stream>>>(dw, dwb, W4);  // aliases uwb; after k2
    k3_down<<<MAXJ * 4, 512, 0, stream>>>(h, dwb, cnt, off, token_list, roww, jobs, njobs, out);
}